// Round 3
// baseline (518.409 us; speedup 1.0000x reference)
//
#include <hip/hip_runtime.h>
#include <hip/hip_bf16.h>

#define N_VOX 120000

typedef __attribute__((ext_vector_type(8))) __bf16 bf16x8;
typedef __attribute__((ext_vector_type(4))) float floatx4;
using bf16 = __hip_bfloat16;

__device__ __forceinline__ float b2f(bf16 v) { return __bfloat162float(v); }
__device__ __forceinline__ bf16 f2b(float v) { return __float2bfloat16(v); }

// ---------------------------------------------------------------------------
// Gather-GEMM conv stage: tout[n,:] = lrelu( sum_k uin[nbr[n,k],:] @ W[k] )
// uin: [N_VOX+1, CIN] bf16, row N_VOX is all zeros (missing-neighbor pad).
// bpack: B fragments prepacked per (kstep, cotile, lane): [KSTEPS][NT][64][8].
// Each wave computes a 16-row M-tile across all COUT columns.
// A-frag (m89/m120 layout): lane holds A[m=lane&15][k=(lane>>4)*8+j] = 8
// contiguous channels of one gathered neighbor row -> one 16B load / k-step.
// ---------------------------------------------------------------------------
template<int CIN, int COUT, bool STATS>
__global__ __launch_bounds__(256) void conv_kernel(
    const bf16* __restrict__ uin,
    const int*  __restrict__ nbr,     // [N_VOX, 9]
    const bf16* __restrict__ bpack,
    bf16* __restrict__ tout,          // [N_VOX, COUT] (rows 0..N-1 only)
    float* __restrict__ stats)        // [2][64]: sum, sumsq
{
    constexpr int NT = COUT / 16;
    constexpr int K = 9 * CIN;
    constexpr int KSTEPS = (K + 31) / 32;

    const int lane = threadIdx.x & 63;
    const int wave = threadIdx.x >> 6;
    const int m    = lane & 15;
    const int quad = lane >> 4;
    const int rowbase = blockIdx.x * 64 + wave * 16;
    const int row_m = rowbase + m;    // row this lane gathers A for

    floatx4 acc[NT];
#pragma unroll
    for (int c = 0; c < NT; ++c) acc[c] = (floatx4){0.f, 0.f, 0.f, 0.f};

    const bf16x8* bp = reinterpret_cast<const bf16x8*>(bpack);

#pragma unroll
    for (int t = 0; t < KSTEPS; ++t) {
        const int kb = (t * 4 + quad) * 8;
        int nb, cib;
        if constexpr (K % 32 != 0) {
            // tail kstep: k >= K lanes read a safe dummy (B is packed zero there)
            const bool valid = kb < K;
            nb  = valid ? kb / CIN : 0;
            cib = valid ? kb % CIN : 0;
        } else {
            nb  = kb / CIN;
            cib = kb % CIN;
        }
        const int idx = nbr[row_m * 9 + nb];                  // == N_VOX if missing
        const bf16x8 a = *reinterpret_cast<const bf16x8*>(uin + idx * CIN + cib);
#pragma unroll
        for (int c = 0; c < NT; ++c) {
            const bf16x8 b = bp[(t * NT + c) * 64 + lane];
            acc[c] = __builtin_amdgcn_mfma_f32_16x16x32_bf16(a, b, acc[c], 0, 0, 0);
        }
    }

    // Epilogue: leaky-relu, store bf16, optional per-channel sum/sumsq stats.
    // C/D layout (m89): col(ch) = lane&15, row = quad*4 + reg.
    __shared__ float sS[64];
    __shared__ float sS2[64];
    if constexpr (STATS) {
        for (int i = threadIdx.x; i < COUT; i += 256) { sS[i] = 0.f; sS2[i] = 0.f; }
        __syncthreads();
    }
#pragma unroll
    for (int c = 0; c < NT; ++c) {
        const int ch = c * 16 + m;
        float ps = 0.f, ps2 = 0.f;
#pragma unroll
        for (int i = 0; i < 4; ++i) {
            const int r = rowbase + quad * 4 + i;
            float v = acc[c][i];
            v = v > 0.f ? v : 0.01f * v;
            tout[r * COUT + ch] = f2b(v);
            ps += v; ps2 += v * v;
        }
        if constexpr (STATS) {
            atomicAdd(&sS[ch], ps);
            atomicAdd(&sS2[ch], ps2);
        }
    }
    if constexpr (STATS) {
        __syncthreads();
        for (int i = threadIdx.x; i < COUT; i += 256) {
            atomicAdd(&stats[i],      sS[i]);
            atomicAdd(&stats[64 + i], sS2[i]);
        }
    }
}

// ---------------------------------------------------------------------------
// In-place BN affine on t[N_VOX,C] (bf16), writes zero pad row N_VOX.
// g, b are float32 (reference dtype).
// ---------------------------------------------------------------------------
template<int C>
__global__ __launch_bounds__(256) void bnapply_kernel(
    bf16* t, const float* __restrict__ s,
    const float* __restrict__ g, const float* __restrict__ b)
{
    const int idx = blockIdx.x * 256 + threadIdx.x;
    if (idx >= (N_VOX + 1) * C) return;
    if (idx >= N_VOX * C) { t[idx] = f2b(0.f); return; }
    const int ch = idx & (C - 1);
    const float inv_n = 1.0f / N_VOX;
    const float mu = s[ch] * inv_n;
    const float var = fmaxf(s[64 + ch] * inv_n - mu * mu, 0.f);
    const float a = rsqrtf(var + 1e-5f) * g[ch];
    const float c0 = b[ch] - mu * a;
    t[idx] = f2b(a * b2f(t[idx]) + c0);
}

// ---------------------------------------------------------------------------
// out = BN_a(ta) + BN_b(tb); OUT = bf16 (intermediate y, with zero pad row)
// or float (final d_out). Elementwise in-place safe for same-width types.
// ---------------------------------------------------------------------------
template<int C, bool ZROW, typename OUT>
__global__ __launch_bounds__(256) void addbn_kernel(
    const bf16* ta, const float* __restrict__ sa,
    const float* __restrict__ ga, const float* __restrict__ ba,
    const bf16* tb, const float* __restrict__ sb,
    const float* __restrict__ gb, const float* __restrict__ bb,
    OUT* out)
{
    const int total = (N_VOX + (ZROW ? 1 : 0)) * C;
    const int idx = blockIdx.x * 256 + threadIdx.x;
    if (idx >= total) return;
    if (ZROW && idx >= N_VOX * C) { out[idx] = (OUT)0.f; return; }
    const int ch = idx & (C - 1);
    const float inv_n = 1.0f / N_VOX;
    const float ma = sa[ch] * inv_n;
    const float va = fmaxf(sa[64 + ch] * inv_n - ma * ma, 0.f);
    const float aa = rsqrtf(va + 1e-5f) * ga[ch];
    const float ca = ba[ch] - ma * aa;
    const float mb = sb[ch] * inv_n;
    const float vb = fmaxf(sb[64 + ch] * inv_n - mb * mb, 0.f);
    const float ab = rsqrtf(vb + 1e-5f) * gb[ch];
    const float cb = bb[ch] - mb * ab;
    const float v = aa * b2f(ta[idx]) + ca + ab * b2f(tb[idx]) + cb;
    if constexpr (sizeof(OUT) == 2) out[idx] = f2b(v);
    else                            out[idx] = v;
}

// ---------------------------------------------------------------------------
// Prep (single kernel, regions by global id):
//  1) u0 = bf16(x) with zero pad row          [x is float32 per reference]
//  2) pack all 8 weights (float32) into bf16 MFMA B-fragment order:
//     B[k = t*32 + (lane>>4)*8 + j][n = c*16 + (lane&15)], zeros for k >= 9*CIN
//  3) zero stats buffers + zero pad row of u3
// ---------------------------------------------------------------------------
#define PACK_TOTAL 139264
__global__ __launch_bounds__(256) void prep_kernel(
    const float* __restrict__ x,
    const float* W0, const float* W1, const float* W2, const float* W3,
    const float* W4, const float* W5, const float* W6, const float* W7,
    bf16* __restrict__ u0, bf16* __restrict__ bpack,
    float* __restrict__ stats, bf16* __restrict__ u3)
{
    const int gid = blockIdx.x * 256 + threadIdx.x;
    constexpr int NXE = (N_VOX + 1) * 16;
    if (gid < NXE) {
        u0[gid] = (gid < N_VOX * 16) ? f2b(x[gid]) : f2b(0.f);
        return;
    }
    int p = gid - NXE;
    if (p < PACK_TOTAL) {
        constexpr int cin[8]  = {16, 32, 16, 32, 32, 64, 32, 64};
        constexpr int cout[8] = {32, 32, 32, 32, 64, 64, 64, 64};
        constexpr int offs[9] = {0, 5120, 14336, 19456, 28672, 47104, 83968, 102400, 139264};
        const float* Ws[8] = {W0, W1, W2, W3, W4, W5, W6, W7};
        int w = 0;
        while (p >= offs[w + 1]) ++w;
        const int e = p - offs[w];
        const int CI = cin[w], CO = cout[w];
        const int NTl = CO / 16;
        const int j = e & 7;
        const int lane = (e >> 3) & 63;
        const int rest = e >> 9;
        const int c = rest % NTl;
        const int t = rest / NTl;
        const int ncol = c * 16 + (lane & 15);
        const int k = t * 32 + (lane >> 4) * 8 + j;
        float val = 0.f;
        if (k < 9 * CI) {
            const int nbq = k / CI;
            const int ci = k % CI;
            val = Ws[w][(nbq * CI + ci) * CO + ncol];
        }
        bpack[p] = f2b(val);
        return;
    }
    p -= PACK_TOTAL;
    if (p < 1024) { stats[p] = 0.f; return; }
    p -= 1024;
    if (p < 32) u3[N_VOX * 32 + p] = f2b(0.f);
}

extern "C" void kernel_launch(void* const* d_in, const int* in_sizes, int n_in,
                              void* d_out, int out_size, void* d_ws, size_t ws_size,
                              hipStream_t stream) {
    // Reference dtypes: all float tensors are float32; rulebooks int32.
    const float* x     = (const float*)d_in[0];
    const int* nbr133  = (const int*)d_in[1];
    const int* nbr313  = (const int*)d_in[2];
    const float* W_c1  = (const float*)d_in[3];
    const float* g0    = (const float*)d_in[4];
    const float* b0    = (const float*)d_in[5];
    const float* W_c12 = (const float*)d_in[6];
    const float* g02   = (const float*)d_in[7];
    const float* b02   = (const float*)d_in[8];
    const float* W_c2  = (const float*)d_in[9];
    const float* W_c3  = (const float*)d_in[10];
    const float* g2    = (const float*)d_in[11];
    const float* b2    = (const float*)d_in[12];
    const float* W_r1  = (const float*)d_in[13];
    const float* rg0   = (const float*)d_in[14];
    const float* rb0   = (const float*)d_in[15];
    const float* W_r12 = (const float*)d_in[16];
    const float* rg02  = (const float*)d_in[17];
    const float* rb02  = (const float*)d_in[18];
    const float* W_r2  = (const float*)d_in[19];
    const float* rg1   = (const float*)d_in[20];
    const float* rb1   = (const float*)d_in[21];
    const float* W_r3  = (const float*)d_in[22];
    const float* rg2   = (const float*)d_in[23];
    const float* rb2   = (const float*)d_in[24];

    // --- workspace layout with aliasing; peak ~58 MB --------------------------
    // Def-use schedule (single stream, sequential):
    //   prep:  u0, bpack, stats, u3-pad
    //   conv1: u0 -> B1(R1);  bnapply B1 (+pad)
    //   conv2: B1 -> T2(R3)
    //   conv3: u0 -> u3(R1)   [B1 dead, same buffer; pad row still zero]
    //   conv4: u3 -> T4(R2)
    //   addbn1: T2,T4 -> uy(R3 in-place, bf16, +pad)   [u0,u3,T4 dead after]
    //   conv5: uy -> B5(R4);  bnapply B5 (+pad)
    //   conv6: B5 -> T6 (aliases R0+R1+R2 head region, 19.2MB >= 15.36MB)
    //   conv7: uy -> B7(R4)   [B5 dead];  bnapply B7 (+pad)
    //   conv8: B7 -> T8(R5, bf16)
    //   addbn2: T6,T8 -> d_out (float32)
    char* ws = (char*)d_ws;
    size_t off = 0;
    auto alloc = [&](size_t bytes) -> char* {
        off = (off + 255) & ~(size_t)255;
        char* p = ws + off;
        off += bytes;
        return p;
    };
    const size_t NV = N_VOX;
    bf16* u0   = (bf16*)alloc((NV + 1) * 16 * 2);   // R0: bf16(x) padded; later part of T6
    bf16* B1u3 = (bf16*)alloc((NV + 1) * 32 * 2);   // R1: B1 then u3; later part of T6
    bf16* T4   = (bf16*)alloc(NV * 32 * 2);         // R2: later part of T6
    bf16* T2uy = (bf16*)alloc((NV + 1) * 32 * 2);   // R3: T2 then uy (in-place addbn)
    bf16* B5B7 = (bf16*)alloc((NV + 1) * 64 * 2);   // R4: B5 then B7
    bf16* T8   = (bf16*)alloc(NV * 64 * 2);         // R5
    bf16* bpack = (bf16*)alloc((size_t)PACK_TOTAL * 2);
    float* stats = (float*)alloc(1024 * 4);         // 8 slots x [sum[64], sumsq[64]]
    bf16* T6 = (bf16*)ws;                           // alias R0..R2 (19.2MB available)

    float* st1 = stats + 0 * 128;
    float* st2 = stats + 1 * 128;
    float* st4 = stats + 3 * 128;
    float* st5 = stats + 4 * 128;
    float* st6 = stats + 5 * 128;
    float* st7 = stats + 6 * 128;
    float* st8 = stats + 7 * 128;

    bf16* bp0 = bpack + 0;       // W_c1  (16->32)
    bf16* bp1 = bpack + 5120;    // W_c12 (32->32)
    bf16* bp2 = bpack + 14336;   // W_c2  (16->32)
    bf16* bp3 = bpack + 19456;   // W_c3  (32->32)
    bf16* bp4 = bpack + 28672;   // W_r1  (32->64)
    bf16* bp5 = bpack + 47104;   // W_r12 (64->64)
    bf16* bp6 = bpack + 83968;   // W_r2  (32->64)
    bf16* bp7 = bpack + 102400;  // W_r3  (64->64)

    const int prep_total = (N_VOX + 1) * 16 + PACK_TOTAL + 1024 + 32;
    prep_kernel<<<(prep_total + 255) / 256, 256, 0, stream>>>(
        x, W_c1, W_c12, W_c2, W_c3, W_r1, W_r12, W_r2, W_r3, u0, bpack, stats, B1u3);

    const int CB = N_VOX / 64;  // 1875, exact
    const int E32 = ((N_VOX + 1) * 32 + 255) / 256;
    const int E64 = ((N_VOX + 1) * 64 + 255) / 256;

    // ResContextBlock
    conv_kernel<16, 32, true><<<CB, 256, 0, stream>>>(u0, nbr133, bp0, B1u3, st1);
    bnapply_kernel<32><<<E32, 256, 0, stream>>>(B1u3, st1, g0, b0);
    conv_kernel<32, 32, true><<<CB, 256, 0, stream>>>(B1u3, nbr313, bp1, T2uy, st2);
    conv_kernel<16, 32, false><<<CB, 256, 0, stream>>>(u0, nbr313, bp2, B1u3, nullptr);
    conv_kernel<32, 32, true><<<CB, 256, 0, stream>>>(B1u3, nbr133, bp3, T4, st4);
    addbn_kernel<32, true, bf16><<<E32, 256, 0, stream>>>(
        T2uy, st2, g02, b02, T4, st4, g2, b2, T2uy);
    // ResBlock
    conv_kernel<32, 64, true><<<CB, 256, 0, stream>>>(T2uy, nbr313, bp4, B5B7, st5);
    bnapply_kernel<64><<<E64, 256, 0, stream>>>(B5B7, st5, rg0, rb0);
    conv_kernel<64, 64, true><<<CB, 256, 0, stream>>>(B5B7, nbr133, bp5, T6, st6);
    conv_kernel<32, 64, true><<<CB, 256, 0, stream>>>(T2uy, nbr133, bp6, B5B7, st7);
    bnapply_kernel<64><<<E64, 256, 0, stream>>>(B5B7, st7, rg1, rb1);
    conv_kernel<64, 64, true><<<CB, 256, 0, stream>>>(B5B7, nbr313, bp7, T8, st8);
    addbn_kernel<64, false, float><<<(N_VOX * 64 + 255) / 256, 256, 0, stream>>>(
        T6, st6, rg02, rb02, T8, st8, rg2, rb2, (float*)d_out);
}